// Round 2
// baseline (738.574 us; speedup 1.0000x reference)
//
#include <hip/hip_runtime.h>
#include <math.h>

// ---------------------------------------------------------------------------
// Transpose W[64][K] -> Bt[K][64]  (tiny: <=64KB)
// ---------------------------------------------------------------------------
__global__ void transpose_w(const float* __restrict__ W, float* __restrict__ Bt, int K) {
  int i = blockIdx.x * blockDim.x + threadIdx.x;  // over K*64
  if (i < K * 64) {
    int k = i >> 6, c = i & 63;
    Bt[i] = W[c * K + k];
  }
}

// ---------------------------------------------------------------------------
// C[M,64] = A[M,K] @ Bt[K,64]  — one thread per output row.
// B k-slices are wave-uniform -> SGPR broadcast (s_load), A streamed float4.
// ---------------------------------------------------------------------------
__global__ __launch_bounds__(64) void gemm_rowthread(const float* __restrict__ A,
                                                     const float* __restrict__ Bt,
                                                     float* __restrict__ C,
                                                     int M, int K) {
  int r = blockIdx.x * 64 + threadIdx.x;
  if (r >= M) return;
  float acc[64];
  #pragma unroll
  for (int c = 0; c < 64; ++c) acc[c] = 0.f;

  const float* Arow = A + (size_t)r * K;
  for (int k4 = 0; k4 < K; k4 += 4) {
    float4 a = *(const float4*)(Arow + k4);
    #pragma unroll
    for (int kk = 0; kk < 4; ++kk) {
      const float* __restrict__ brow = Bt + (size_t)(k4 + kk) * 64;  // uniform addr
      float av = (kk == 0) ? a.x : (kk == 1) ? a.y : (kk == 2) ? a.z : a.w;
      #pragma unroll
      for (int c = 0; c < 64; ++c) acc[c] += av * brow[c];
    }
  }
  float* Crow = C + (size_t)r * 64;
  #pragma unroll
  for (int c4 = 0; c4 < 16; ++c4) {
    *(float4*)(Crow + c4 * 4) = make_float4(acc[c4 * 4], acc[c4 * 4 + 1],
                                            acc[c4 * 4 + 2], acc[c4 * 4 + 3]);
  }
}

// ---------------------------------------------------------------------------
// CSR build: count -> scan -> scatter
// ---------------------------------------------------------------------------
__global__ void count_deg(const int* __restrict__ dst, int* __restrict__ cnt, int E) {
  int i = blockIdx.x * blockDim.x + threadIdx.x;
  if (i < E) atomicAdd(&cnt[dst[i]], 1);
}

__global__ __launch_bounds__(1024) void scan_deg(int* __restrict__ cnt,
                                                 int* __restrict__ offsets, int n) {
  __shared__ int waveSums[16];
  const int t = threadIdx.x;
  const int lane = t & 63, wave = t >> 6;
  const int PER = 8;
  const int CHUNK = 1024 * PER;
  int running = 0;
  for (int c0 = 0; c0 < n; c0 += CHUNK) {
    int idx0 = c0 + t * PER;
    int v[PER];
    int s = 0;
    #pragma unroll
    for (int j = 0; j < PER; ++j) {
      int i = idx0 + j;
      int x = (i < n) ? cnt[i] : 0;
      v[j] = s;
      s += x;
    }
    int inc = s;
    #pragma unroll
    for (int d = 1; d < 64; d <<= 1) {
      int o = __shfl_up(inc, d, 64);
      if (lane >= d) inc += o;
    }
    int excl = inc - s;
    if (lane == 63) waveSums[wave] = inc;
    __syncthreads();
    int waveBase = 0, total = 0;
    #pragma unroll
    for (int w = 0; w < 16; ++w) {
      int ws_v = waveSums[w];
      if (w < wave) waveBase += ws_v;
      total += ws_v;
    }
    int base = running + waveBase + excl;
    #pragma unroll
    for (int j = 0; j < PER; ++j) {
      int i = idx0 + j;
      if (i < n) {
        offsets[i] = base + v[j];
        cnt[i] = base + v[j];
      }
    }
    running += total;
    __syncthreads();
  }
  if (t == 0) offsets[n] = running;
}

__global__ void scatter_edges(const int* __restrict__ dst, const int* __restrict__ src,
                              int* __restrict__ cursor, int* __restrict__ edgeSrc, int E) {
  int i = blockIdx.x * blockDim.x + threadIdx.x;
  if (i < E) {
    int pos = atomicAdd(&cursor[dst[i]], 1);
    edgeSrc[pos] = src[i];
  }
}

// ---------------------------------------------------------------------------
// One wave per dst: online-softmax aggregation, 4-edge ILP batching.
// Whole neighbor chunk's src indices loaded coalesced (lane j = edge j),
// broadcast via __shfl.
// ---------------------------------------------------------------------------
__global__ __launch_bounds__(256) void aggregate(const float* __restrict__ z,
                                                 const float* __restrict__ df,
                                                 const int* __restrict__ offsets,
                                                 const int* __restrict__ edgeSrc,
                                                 float* __restrict__ out, int N) {
  int gwave = (blockIdx.x * blockDim.x + threadIdx.x) >> 6;
  int lane = threadIdx.x & 63;
  if (gwave >= N) return;
  const int d = gwave;
  const float dfv = df[(size_t)d * 64 + lane];
  const int beg = offsets[d];
  const int end = offsets[d + 1];

  float m = -INFINITY, l = 0.f, acc = 0.f;
  for (int j0 = beg; j0 < end; j0 += 64) {
    int cnt = min(64, end - j0);
    int j = j0 + lane;
    int sv = (j < end) ? edgeSrc[j] : 0;
    int jj = 0;
    for (; jj + 4 <= cnt; jj += 4) {
      int s0 = __shfl(sv, jj, 64);
      int s1 = __shfl(sv, jj + 1, 64);
      int s2 = __shfl(sv, jj + 2, 64);
      int s3 = __shfl(sv, jj + 3, 64);
      float z0 = z[(size_t)s0 * 64 + lane];
      float z1 = z[(size_t)s1 * 64 + lane];
      float z2 = z[(size_t)s2 * 64 + lane];
      float z3 = z[(size_t)s3 * 64 + lane];
      float p0 = z0 * dfv, p1 = z1 * dfv, p2 = z2 * dfv, p3 = z3 * dfv;
      #pragma unroll
      for (int o = 32; o > 0; o >>= 1) {
        p0 += __shfl_xor(p0, o, 64);
        p1 += __shfl_xor(p1, o, 64);
        p2 += __shfl_xor(p2, o, 64);
        p3 += __shfl_xor(p3, o, 64);
      }
      float mm = fmaxf(fmaxf(p0, p1), fmaxf(p2, p3));
      float nm = fmaxf(m, mm);
      float alpha = __expf(m - nm);
      float w0 = __expf(p0 - nm);
      float w1 = __expf(p1 - nm);
      float w2 = __expf(p2 - nm);
      float w3 = __expf(p3 - nm);
      l = l * alpha + (w0 + w1) + (w2 + w3);
      acc = acc * alpha + (w0 * z0 + w1 * z1) + (w2 * z2 + w3 * z3);
      m = nm;
    }
    for (; jj < cnt; ++jj) {
      int s = __shfl(sv, jj, 64);
      float zv = z[(size_t)s * 64 + lane];
      float p = zv * dfv;
      #pragma unroll
      for (int o = 32; o > 0; o >>= 1) p += __shfl_xor(p, o, 64);
      float nm = fmaxf(m, p);
      float alpha = __expf(m - nm);
      float w = __expf(p - nm);
      l = l * alpha + w;
      acc = acc * alpha + w * zv;
      m = nm;
    }
  }
  out[(size_t)d * 64 + lane] = (l > 0.f) ? (acc / l) : 0.f;
}

// ---------------------------------------------------------------------------
extern "C" void kernel_launch(void* const* d_in, const int* in_sizes, int n_in,
                              void* d_out, int out_size, void* d_ws, size_t ws_size,
                              hipStream_t stream) {
  const float* h     = (const float*)d_in[0];  // [N,256]
  const float* feat  = (const float*)d_in[1];  // [N,64]
  const float* W_fc  = (const float*)d_in[2];  // [64,256]
  const float* W_dst = (const float*)d_in[3];  // [64,64]
  const int*   src   = (const int*)d_in[4];    // [E]
  const int*   dst   = (const int*)d_in[5];    // [E]
  float* out = (float*)d_out;

  const int N = in_sizes[1] / 64;        // 100000
  const int E = in_sizes[4];             // 1600000
  const int IN_DIM = in_sizes[0] / N;    // 256
  const int FEAT_DIM = 64;

  // workspace layout
  char* ws = (char*)d_ws;
  float* z  = (float*)ws;                        // N*64 f32
  float* df = z + (size_t)N * 64;                // N*64 f32
  int* offsets = (int*)(df + (size_t)N * 64);    // N+1
  int* cursor  = offsets + (N + 1);              // N
  int* edgeSrc = cursor + N;                     // E
  float* Bt_fc  = (float*)(edgeSrc + E);         // IN_DIM*64
  float* Bt_dst = Bt_fc + (size_t)IN_DIM * 64;   // FEAT_DIM*64

  hipMemsetAsync(cursor, 0, sizeof(int) * (size_t)N, stream);

  transpose_w<<<(IN_DIM * 64 + 255) / 256, 256, 0, stream>>>(W_fc, Bt_fc, IN_DIM);
  transpose_w<<<(FEAT_DIM * 64 + 255) / 256, 256, 0, stream>>>(W_dst, Bt_dst, FEAT_DIM);

  gemm_rowthread<<<(N + 63) / 64, 64, 0, stream>>>(h, Bt_fc, z, N, IN_DIM);
  gemm_rowthread<<<(N + 63) / 64, 64, 0, stream>>>(feat, Bt_dst, df, N, FEAT_DIM);

  int egrid = (E + 255) / 256;
  count_deg<<<egrid, 256, 0, stream>>>(dst, cursor, E);
  scan_deg<<<1, 1024, 0, stream>>>(cursor, offsets, N);
  scatter_edges<<<egrid, 256, 0, stream>>>(dst, src, cursor, edgeSrc, E);

  aggregate<<<(N + 3) / 4, 256, 0, stream>>>(z, df, offsets, edgeSrc, out, N);
}

// Round 3
// 566.098 us; speedup vs baseline: 1.3047x; 1.3047x over previous
//
#include <hip/hip_runtime.h>
#include <math.h>

// ---------------------------------------------------------------------------
// C[M,64] = A[M,K] @ B[64,K]^T — LDS-tiled, 128x64 block tile, 8x4 microtile.
// ---------------------------------------------------------------------------
__global__ __launch_bounds__(256) void gemm_nt128(const float* __restrict__ A,
                                                  const float* __restrict__ B,
                                                  float* __restrict__ C,
                                                  int M, int K) {
  __shared__ float As[32][132];  // [k][m], padded
  __shared__ float Bs[32][68];   // [k][n], padded
  const int t = threadIdx.x;
  const int rBase = blockIdx.x * 128;
  const int tx = t & 15, ty = t >> 4;
  const int n0 = tx * 4, m0 = ty * 8;
  float acc[8][4] = {};

  for (int kb = 0; kb < K; kb += 32) {
    // stage A: 128 rows x 32 k = 1024 float4, 4 per thread
    #pragma unroll
    for (int q = 0; q < 4; ++q) {
      int f = t + q * 256;
      int row = f >> 3;
      int kq = f & 7;
      int gr = rBase + row;
      float4 av = make_float4(0.f, 0.f, 0.f, 0.f);
      if (gr < M) av = *(const float4*)(A + (size_t)gr * K + kb + kq * 4);
      As[kq * 4 + 0][row] = av.x;
      As[kq * 4 + 1][row] = av.y;
      As[kq * 4 + 2][row] = av.z;
      As[kq * 4 + 3][row] = av.w;
    }
    // stage B: 64 rows x 32 k = 512 float4, 2 per thread
    #pragma unroll
    for (int q = 0; q < 2; ++q) {
      int f = t + q * 256;
      int row = f >> 3;  // output col
      int kq = f & 7;
      float4 bv = *(const float4*)(B + (size_t)row * K + kb + kq * 4);
      Bs[kq * 4 + 0][row] = bv.x;
      Bs[kq * 4 + 1][row] = bv.y;
      Bs[kq * 4 + 2][row] = bv.z;
      Bs[kq * 4 + 3][row] = bv.w;
    }
    __syncthreads();
    #pragma unroll
    for (int k = 0; k < 32; ++k) {
      float4 a0 = *(const float4*)&As[k][m0];
      float4 a1 = *(const float4*)&As[k][m0 + 4];
      float4 b  = *(const float4*)&Bs[k][n0];
      float am[8] = {a0.x, a0.y, a0.z, a0.w, a1.x, a1.y, a1.z, a1.w};
      #pragma unroll
      for (int i = 0; i < 8; ++i) {
        acc[i][0] += am[i] * b.x;
        acc[i][1] += am[i] * b.y;
        acc[i][2] += am[i] * b.z;
        acc[i][3] += am[i] * b.w;
      }
    }
    __syncthreads();
  }
  #pragma unroll
  for (int i = 0; i < 8; ++i) {
    int gr = rBase + m0 + i;
    if (gr < M) {
      *(float4*)(C + (size_t)gr * 64 + n0) =
          make_float4(acc[i][0], acc[i][1], acc[i][2], acc[i][3]);
    }
  }
}

// ---------------------------------------------------------------------------
// CSR build: count -> hierarchical scan (A: tile sums, C: apply) -> scatter
// ---------------------------------------------------------------------------
__global__ void count_deg(const int* __restrict__ dst, int* __restrict__ cnt, int E) {
  int i = blockIdx.x * blockDim.x + threadIdx.x;
  if (i < E) atomicAdd(&cnt[dst[i]], 1);
}

#define SCAN_TILE 4096  // 1024 threads x 4

__global__ __launch_bounds__(1024) void scanA(const int* __restrict__ cnt,
                                              int* __restrict__ blockSums, int n) {
  __shared__ int waveSums[16];
  const int t = threadIdx.x;
  const int lane = t & 63, wave = t >> 6;
  int i0 = blockIdx.x * SCAN_TILE + t * 4;
  int s = 0;
  #pragma unroll
  for (int j = 0; j < 4; ++j) {
    int i = i0 + j;
    if (i < n) s += cnt[i];
  }
  #pragma unroll
  for (int o = 32; o > 0; o >>= 1) s += __shfl_xor(s, o, 64);
  if (lane == 0) waveSums[wave] = s;
  __syncthreads();
  if (t == 0) {
    int tot = 0;
    #pragma unroll
    for (int w = 0; w < 16; ++w) tot += waveSums[w];
    blockSums[blockIdx.x] = tot;
  }
}

// writes offsets[i] and cursor[i] = exclusive prefix; offsets[n] = E (known).
__global__ __launch_bounds__(1024) void scanC(const int* __restrict__ cnt,
                                              const int* __restrict__ blockSums,
                                              int* __restrict__ offsets,
                                              int* __restrict__ cursor,
                                              int n, int E) {
  __shared__ int waveSums[16];
  const int t = threadIdx.x;
  const int lane = t & 63, wave = t >> 6;
  const int bid = blockIdx.x;

  int blockBase = 0;
  for (int b = 0; b < bid; ++b) blockBase += blockSums[b];

  int i0 = bid * SCAN_TILE + t * 4;
  int x[4], v[4];
  int s = 0;
  #pragma unroll
  for (int j = 0; j < 4; ++j) {
    int i = i0 + j;
    x[j] = (i < n) ? cnt[i] : 0;
    v[j] = s;
    s += x[j];
  }
  int inc = s;
  #pragma unroll
  for (int d = 1; d < 64; d <<= 1) {
    int o = __shfl_up(inc, d, 64);
    if (lane >= d) inc += o;
  }
  int excl = inc - s;
  if (lane == 63) waveSums[wave] = inc;
  __syncthreads();
  int waveBase = 0;
  #pragma unroll
  for (int w = 0; w < 16; ++w)
    if (w < wave) waveBase += waveSums[w];
  int base = blockBase + waveBase + excl;
  #pragma unroll
  for (int j = 0; j < 4; ++j) {
    int i = i0 + j;
    if (i < n) {
      offsets[i] = base + v[j];
      cursor[i] = base + v[j];
    }
  }
  if (bid == 0 && t == 0) offsets[n] = E;
}

__global__ void scatter_edges(const int* __restrict__ dst, const int* __restrict__ src,
                              int* __restrict__ cursor, int* __restrict__ edgeSrc, int E) {
  int i = blockIdx.x * blockDim.x + threadIdx.x;
  if (i < E) {
    int pos = atomicAdd(&cursor[dst[i]], 1);
    edgeSrc[pos] = src[i];
  }
}

// ---------------------------------------------------------------------------
// One wave per dst: online-softmax aggregation, 4-edge ILP batching.
// ---------------------------------------------------------------------------
__global__ __launch_bounds__(256) void aggregate(const float* __restrict__ z,
                                                 const float* __restrict__ df,
                                                 const int* __restrict__ offsets,
                                                 const int* __restrict__ edgeSrc,
                                                 float* __restrict__ out, int N) {
  int gwave = (blockIdx.x * blockDim.x + threadIdx.x) >> 6;
  int lane = threadIdx.x & 63;
  if (gwave >= N) return;
  const int d = gwave;
  const float dfv = df[(size_t)d * 64 + lane];
  const int beg = offsets[d];
  const int end = offsets[d + 1];

  float m = -INFINITY, l = 0.f, acc = 0.f;
  for (int j0 = beg; j0 < end; j0 += 64) {
    int cnt = min(64, end - j0);
    int j = j0 + lane;
    int sv = (j < end) ? edgeSrc[j] : 0;
    int jj = 0;
    for (; jj + 4 <= cnt; jj += 4) {
      int s0 = __shfl(sv, jj, 64);
      int s1 = __shfl(sv, jj + 1, 64);
      int s2 = __shfl(sv, jj + 2, 64);
      int s3 = __shfl(sv, jj + 3, 64);
      float z0 = z[(size_t)s0 * 64 + lane];
      float z1 = z[(size_t)s1 * 64 + lane];
      float z2 = z[(size_t)s2 * 64 + lane];
      float z3 = z[(size_t)s3 * 64 + lane];
      float p0 = z0 * dfv, p1 = z1 * dfv, p2 = z2 * dfv, p3 = z3 * dfv;
      #pragma unroll
      for (int o = 32; o > 0; o >>= 1) {
        p0 += __shfl_xor(p0, o, 64);
        p1 += __shfl_xor(p1, o, 64);
        p2 += __shfl_xor(p2, o, 64);
        p3 += __shfl_xor(p3, o, 64);
      }
      float mm = fmaxf(fmaxf(p0, p1), fmaxf(p2, p3));
      float nm = fmaxf(m, mm);
      float alpha = __expf(m - nm);
      float w0 = __expf(p0 - nm);
      float w1 = __expf(p1 - nm);
      float w2 = __expf(p2 - nm);
      float w3 = __expf(p3 - nm);
      l = l * alpha + (w0 + w1) + (w2 + w3);
      acc = acc * alpha + (w0 * z0 + w1 * z1) + (w2 * z2 + w3 * z3);
      m = nm;
    }
    for (; jj < cnt; ++jj) {
      int s = __shfl(sv, jj, 64);
      float zv = z[(size_t)s * 64 + lane];
      float p = zv * dfv;
      #pragma unroll
      for (int o = 32; o > 0; o >>= 1) p += __shfl_xor(p, o, 64);
      float nm = fmaxf(m, p);
      float alpha = __expf(m - nm);
      float w = __expf(p - nm);
      l = l * alpha + w;
      acc = acc * alpha + w * zv;
      m = nm;
    }
  }
  out[(size_t)d * 64 + lane] = (l > 0.f) ? (acc / l) : 0.f;
}

// ---------------------------------------------------------------------------
extern "C" void kernel_launch(void* const* d_in, const int* in_sizes, int n_in,
                              void* d_out, int out_size, void* d_ws, size_t ws_size,
                              hipStream_t stream) {
  const float* h     = (const float*)d_in[0];  // [N,256]
  const float* feat  = (const float*)d_in[1];  // [N,64]
  const float* W_fc  = (const float*)d_in[2];  // [64,256]
  const float* W_dst = (const float*)d_in[3];  // [64,64]
  const int*   src   = (const int*)d_in[4];    // [E]
  const int*   dst   = (const int*)d_in[5];    // [E]
  float* out = (float*)d_out;

  const int N = in_sizes[1] / 64;        // 100000
  const int E = in_sizes[4];             // 1600000
  const int IN_DIM = in_sizes[0] / N;    // 256
  const int FEAT_DIM = 64;

  // workspace layout
  char* ws = (char*)d_ws;
  float* z  = (float*)ws;                        // N*64 f32
  float* df = z + (size_t)N * 64;                // N*64 f32
  int* offsets = (int*)(df + (size_t)N * 64);    // N+1
  int* cursor  = offsets + (N + 1);              // N
  int* edgeSrc = cursor + N;                     // E
  int* blockSums = edgeSrc + E;                  // ~25

  hipMemsetAsync(cursor, 0, sizeof(int) * (size_t)N, stream);

  gemm_nt128<<<(N + 127) / 128, 256, 0, stream>>>(h, W_fc, z, N, IN_DIM);
  gemm_nt128<<<(N + 127) / 128, 256, 0, stream>>>(feat, W_dst, df, N, FEAT_DIM);

  int egrid = (E + 255) / 256;
  count_deg<<<egrid, 256, 0, stream>>>(dst, cursor, E);

  int sgrid = (N + SCAN_TILE - 1) / SCAN_TILE;   // 25
  scanA<<<sgrid, 1024, 0, stream>>>(cursor, blockSums, N);
  scanC<<<sgrid, 1024, 0, stream>>>(cursor, blockSums, offsets, cursor, N, E);

  scatter_edges<<<egrid, 256, 0, stream>>>(dst, src, cursor, edgeSrc, E);

  aggregate<<<(N + 3) / 4, 256, 0, stream>>>(z, df, offsets, edgeSrc, out, N);
}

// Round 4
// 550.327 us; speedup vs baseline: 1.3421x; 1.0287x over previous
//
#include <hip/hip_runtime.h>
#include <math.h>

// ---------------------------------------------------------------------------
// C[M,64] = A[M,K] @ B[64,K]^T — LDS-tiled, 128x64 block tile, 8x4 microtile.
// ---------------------------------------------------------------------------
__global__ __launch_bounds__(256) void gemm_nt128(const float* __restrict__ A,
                                                  const float* __restrict__ B,
                                                  float* __restrict__ C,
                                                  int M, int K) {
  __shared__ float As[32][132];  // [k][m], padded
  __shared__ float Bs[32][68];   // [k][n], padded
  const int t = threadIdx.x;
  const int rBase = blockIdx.x * 128;
  const int tx = t & 15, ty = t >> 4;
  const int n0 = tx * 4, m0 = ty * 8;
  float acc[8][4] = {};

  for (int kb = 0; kb < K; kb += 32) {
    #pragma unroll
    for (int q = 0; q < 4; ++q) {
      int f = t + q * 256;
      int row = f >> 3;
      int kq = f & 7;
      int gr = rBase + row;
      float4 av = make_float4(0.f, 0.f, 0.f, 0.f);
      if (gr < M) av = *(const float4*)(A + (size_t)gr * K + kb + kq * 4);
      As[kq * 4 + 0][row] = av.x;
      As[kq * 4 + 1][row] = av.y;
      As[kq * 4 + 2][row] = av.z;
      As[kq * 4 + 3][row] = av.w;
    }
    #pragma unroll
    for (int q = 0; q < 2; ++q) {
      int f = t + q * 256;
      int row = f >> 3;
      int kq = f & 7;
      float4 bv = *(const float4*)(B + (size_t)row * K + kb + kq * 4);
      Bs[kq * 4 + 0][row] = bv.x;
      Bs[kq * 4 + 1][row] = bv.y;
      Bs[kq * 4 + 2][row] = bv.z;
      Bs[kq * 4 + 3][row] = bv.w;
    }
    __syncthreads();
    #pragma unroll
    for (int k = 0; k < 32; ++k) {
      float4 a0 = *(const float4*)&As[k][m0];
      float4 a1 = *(const float4*)&As[k][m0 + 4];
      float4 b  = *(const float4*)&Bs[k][n0];
      float am[8] = {a0.x, a0.y, a0.z, a0.w, a1.x, a1.y, a1.z, a1.w};
      #pragma unroll
      for (int i = 0; i < 8; ++i) {
        acc[i][0] += am[i] * b.x;
        acc[i][1] += am[i] * b.y;
        acc[i][2] += am[i] * b.z;
        acc[i][3] += am[i] * b.w;
      }
    }
    __syncthreads();
  }
  #pragma unroll
  for (int i = 0; i < 8; ++i) {
    int gr = rBase + m0 + i;
    if (gr < M) {
      *(float4*)(C + (size_t)gr * 64 + n0) =
          make_float4(acc[i][0], acc[i][1], acc[i][2], acc[i][3]);
    }
  }
}

// ---------------------------------------------------------------------------
// CSR build: count -> hierarchical scan -> scatter
// ---------------------------------------------------------------------------
__global__ void count_deg(const int* __restrict__ dst, int* __restrict__ cnt, int E) {
  int i = blockIdx.x * blockDim.x + threadIdx.x;
  if (i < E) atomicAdd(&cnt[dst[i]], 1);
}

#define SCAN_TILE 4096  // 1024 threads x 4

__global__ __launch_bounds__(1024) void scanA(const int* __restrict__ cnt,
                                              int* __restrict__ blockSums, int n) {
  __shared__ int waveSums[16];
  const int t = threadIdx.x;
  const int lane = t & 63, wave = t >> 6;
  int i0 = blockIdx.x * SCAN_TILE + t * 4;
  int s = 0;
  #pragma unroll
  for (int j = 0; j < 4; ++j) {
    int i = i0 + j;
    if (i < n) s += cnt[i];
  }
  #pragma unroll
  for (int o = 32; o > 0; o >>= 1) s += __shfl_xor(s, o, 64);
  if (lane == 0) waveSums[wave] = s;
  __syncthreads();
  if (t == 0) {
    int tot = 0;
    #pragma unroll
    for (int w = 0; w < 16; ++w) tot += waveSums[w];
    blockSums[blockIdx.x] = tot;
  }
}

__global__ __launch_bounds__(1024) void scanC(const int* __restrict__ cnt,
                                              const int* __restrict__ blockSums,
                                              int* __restrict__ offsets,
                                              int* __restrict__ cursor,
                                              int n, int E) {
  __shared__ int waveSums[16];
  const int t = threadIdx.x;
  const int lane = t & 63, wave = t >> 6;
  const int bid = blockIdx.x;

  int blockBase = 0;
  for (int b = 0; b < bid; ++b) blockBase += blockSums[b];

  int i0 = bid * SCAN_TILE + t * 4;
  int x[4], v[4];
  int s = 0;
  #pragma unroll
  for (int j = 0; j < 4; ++j) {
    int i = i0 + j;
    x[j] = (i < n) ? cnt[i] : 0;
    v[j] = s;
    s += x[j];
  }
  int inc = s;
  #pragma unroll
  for (int d = 1; d < 64; d <<= 1) {
    int o = __shfl_up(inc, d, 64);
    if (lane >= d) inc += o;
  }
  int excl = inc - s;
  if (lane == 63) waveSums[wave] = inc;
  __syncthreads();
  int waveBase = 0;
  #pragma unroll
  for (int w = 0; w < 16; ++w)
    if (w < wave) waveBase += waveSums[w];
  int base = blockBase + waveBase + excl;
  #pragma unroll
  for (int j = 0; j < 4; ++j) {
    int i = i0 + j;
    if (i < n) {
      offsets[i] = base + v[j];
      cursor[i] = base + v[j];
    }
  }
  if (bid == 0 && t == 0) offsets[n] = E;
}

__global__ void scatter_edges(const int* __restrict__ dst, const int* __restrict__ src,
                              int* __restrict__ cursor, int* __restrict__ edgeSrc, int E) {
  int i = blockIdx.x * blockDim.x + threadIdx.x;
  if (i < E) {
    int pos = atomicAdd(&cursor[dst[i]], 1);
    edgeSrc[pos] = src[i];
  }
}

// ---------------------------------------------------------------------------
// One wave per dst: two-phase exact softmax aggregation.
// Phase 1 (lane=edge): per-lane serial dot product -> e, wave-level max/sum
//   reductions once per 64-edge chunk (12 butterflies per chunk, not 6/edge).
//   df row read via wave-uniform scalar loads.
// Phase 2 (lane=dim): w/s broadcast via v_readlane (scalar pipe, no DS),
//   one z-row gather + FMA per edge (rows L1/L2-warm from phase 1).
// ---------------------------------------------------------------------------
__device__ __forceinline__ float readlane_f(float v, int lane) {
  return __builtin_bit_cast(float, __builtin_amdgcn_readlane(__builtin_bit_cast(int, v), lane));
}

__global__ __launch_bounds__(256) void aggregate(const float* __restrict__ z,
                                                 const float* __restrict__ df,
                                                 const int* __restrict__ offsets,
                                                 const int* __restrict__ edgeSrc,
                                                 float* __restrict__ out, int N) {
  int gwave = (blockIdx.x * blockDim.x + threadIdx.x) >> 6;
  int lane = threadIdx.x & 63;
  if (gwave >= N) return;
  const int d = __builtin_amdgcn_readfirstlane(gwave);  // force wave-uniform SGPR
  const float* __restrict__ dfp = df + (size_t)d * 64;  // uniform base -> s_load
  const int beg = offsets[d];
  const int end = offsets[d + 1];

  float m = -INFINITY, l = 0.f, acc = 0.f;

  for (int j0 = beg; j0 < end; j0 += 64) {
    const int cnt = min(64, end - j0);
    const int j = j0 + lane;
    const bool active = (j < end);
    const int sv = active ? edgeSrc[j] : 0;

    // ---- phase 1: lane = edge, serial dot(z[sv], df[d]) ----
    const float* __restrict__ zr = z + (size_t)sv * 64;
    float e = 0.f;
    #pragma unroll
    for (int c4 = 0; c4 < 16; ++c4) {
      float4 zz = *(const float4*)(zr + c4 * 4);
      float4 bb = *(const float4*)(dfp + c4 * 4);  // wave-uniform -> scalar
      e = fmaf(zz.x, bb.x, e);
      e = fmaf(zz.y, bb.y, e);
      e = fmaf(zz.z, bb.z, e);
      e = fmaf(zz.w, bb.w, e);
    }
    if (!active) e = -INFINITY;

    // chunk max (6 butterflies)
    float mc = e;
    #pragma unroll
    for (int o = 32; o > 0; o >>= 1) mc = fmaxf(mc, __shfl_xor(mc, o, 64));

    float nm = fmaxf(m, mc);
    float alpha = __expf(m - nm);  // first chunk: exp(-inf)=0
    float w = active ? __expf(e - nm) : 0.f;

    // chunk sum (6 butterflies)
    float sc = w;
    #pragma unroll
    for (int o = 32; o > 0; o >>= 1) sc += __shfl_xor(sc, o, 64);

    l = l * alpha + sc;
    acc *= alpha;
    m = nm;

    // ---- phase 2: lane = dim, weighted accumulation ----
    int jj = 0;
    for (; jj + 4 <= cnt; jj += 4) {
      int s0 = __builtin_amdgcn_readlane(sv, jj);
      int s1 = __builtin_amdgcn_readlane(sv, jj + 1);
      int s2 = __builtin_amdgcn_readlane(sv, jj + 2);
      int s3 = __builtin_amdgcn_readlane(sv, jj + 3);
      float w0 = readlane_f(w, jj);
      float w1 = readlane_f(w, jj + 1);
      float w2 = readlane_f(w, jj + 2);
      float w3 = readlane_f(w, jj + 3);
      float z0 = z[(size_t)s0 * 64 + lane];
      float z1 = z[(size_t)s1 * 64 + lane];
      float z2 = z[(size_t)s2 * 64 + lane];
      float z3 = z[(size_t)s3 * 64 + lane];
      acc = fmaf(w0, z0, acc);
      acc = fmaf(w1, z1, acc);
      acc = fmaf(w2, z2, acc);
      acc = fmaf(w3, z3, acc);
    }
    for (; jj < cnt; ++jj) {
      int s0 = __builtin_amdgcn_readlane(sv, jj);
      float w0 = readlane_f(w, jj);
      acc = fmaf(w0, z[(size_t)s0 * 64 + lane], acc);
    }
  }
  out[(size_t)d * 64 + lane] = (l > 0.f) ? (acc / l) : 0.f;
}

// ---------------------------------------------------------------------------
extern "C" void kernel_launch(void* const* d_in, const int* in_sizes, int n_in,
                              void* d_out, int out_size, void* d_ws, size_t ws_size,
                              hipStream_t stream) {
  const float* h     = (const float*)d_in[0];  // [N,256]
  const float* feat  = (const float*)d_in[1];  // [N,64]
  const float* W_fc  = (const float*)d_in[2];  // [64,256]
  const float* W_dst = (const float*)d_in[3];  // [64,64]
  const int*   src   = (const int*)d_in[4];    // [E]
  const int*   dst   = (const int*)d_in[5];    // [E]
  float* out = (float*)d_out;

  const int N = in_sizes[1] / 64;        // 100000
  const int E = in_sizes[4];             // 1600000
  const int IN_DIM = in_sizes[0] / N;    // 256
  const int FEAT_DIM = 64;

  // workspace layout
  char* ws = (char*)d_ws;
  float* z  = (float*)ws;                        // N*64 f32
  float* df = z + (size_t)N * 64;                // N*64 f32
  int* offsets = (int*)(df + (size_t)N * 64);    // N+1
  int* cursor  = offsets + (N + 1);              // N
  int* edgeSrc = cursor + N;                     // E
  int* blockSums = edgeSrc + E;                  // ~25

  hipMemsetAsync(cursor, 0, sizeof(int) * (size_t)N, stream);

  gemm_nt128<<<(N + 127) / 128, 256, 0, stream>>>(h, W_fc, z, N, IN_DIM);
  gemm_nt128<<<(N + 127) / 128, 256, 0, stream>>>(feat, W_dst, df, N, FEAT_DIM);

  int egrid = (E + 255) / 256;
  count_deg<<<egrid, 256, 0, stream>>>(dst, cursor, E);

  int sgrid = (N + SCAN_TILE - 1) / SCAN_TILE;   // 25
  scanA<<<sgrid, 1024, 0, stream>>>(cursor, blockSums, N);
  scanC<<<sgrid, 1024, 0, stream>>>(cursor, blockSums, offsets, cursor, N, E);

  scatter_edges<<<egrid, 256, 0, stream>>>(dst, src, cursor, edgeSrc, E);

  aggregate<<<(N + 3) / 4, 256, 0, stream>>>(z, df, offsets, edgeSrc, out, N);
}

// Round 5
// 467.740 us; speedup vs baseline: 1.5790x; 1.1766x over previous
//
#include <hip/hip_runtime.h>
#include <math.h>

// ---------------------------------------------------------------------------
// C[M,64] = A[M,K] @ B[64,K]^T — LDS-tiled, 128x64 block tile, 8x4 microtile.
// ---------------------------------------------------------------------------
__global__ __launch_bounds__(256) void gemm_nt128(const float* __restrict__ A,
                                                  const float* __restrict__ B,
                                                  float* __restrict__ C,
                                                  int M, int K) {
  __shared__ float As[32][132];  // [k][m], padded
  __shared__ float Bs[32][68];   // [k][n], padded
  const int t = threadIdx.x;
  const int rBase = blockIdx.x * 128;
  const int tx = t & 15, ty = t >> 4;
  const int n0 = tx * 4, m0 = ty * 8;
  float acc[8][4] = {};

  for (int kb = 0; kb < K; kb += 32) {
    #pragma unroll
    for (int q = 0; q < 4; ++q) {
      int f = t + q * 256;
      int row = f >> 3;
      int kq = f & 7;
      int gr = rBase + row;
      float4 av = make_float4(0.f, 0.f, 0.f, 0.f);
      if (gr < M) av = *(const float4*)(A + (size_t)gr * K + kb + kq * 4);
      As[kq * 4 + 0][row] = av.x;
      As[kq * 4 + 1][row] = av.y;
      As[kq * 4 + 2][row] = av.z;
      As[kq * 4 + 3][row] = av.w;
    }
    #pragma unroll
    for (int q = 0; q < 2; ++q) {
      int f = t + q * 256;
      int row = f >> 3;
      int kq = f & 7;
      float4 bv = *(const float4*)(B + (size_t)row * K + kb + kq * 4);
      Bs[kq * 4 + 0][row] = bv.x;
      Bs[kq * 4 + 1][row] = bv.y;
      Bs[kq * 4 + 2][row] = bv.z;
      Bs[kq * 4 + 3][row] = bv.w;
    }
    __syncthreads();
    #pragma unroll
    for (int k = 0; k < 32; ++k) {
      float4 a0 = *(const float4*)&As[k][m0];
      float4 a1 = *(const float4*)&As[k][m0 + 4];
      float4 b  = *(const float4*)&Bs[k][n0];
      float am[8] = {a0.x, a0.y, a0.z, a0.w, a1.x, a1.y, a1.z, a1.w};
      #pragma unroll
      for (int i = 0; i < 8; ++i) {
        acc[i][0] += am[i] * b.x;
        acc[i][1] += am[i] * b.y;
        acc[i][2] += am[i] * b.z;
        acc[i][3] += am[i] * b.w;
      }
    }
    __syncthreads();
  }
  #pragma unroll
  for (int i = 0; i < 8; ++i) {
    int gr = rBase + m0 + i;
    if (gr < M) {
      *(float4*)(C + (size_t)gr * 64 + n0) =
          make_float4(acc[i][0], acc[i][1], acc[i][2], acc[i][3]);
    }
  }
}

// ---------------------------------------------------------------------------
// CSR build via two-level bucket sort.
// Bucket = dst >> 7 (128 nodes per bucket). Dense, full-line writes throughout
// (the old per-edge random scatter caused 16x write amplification: 105MB HBM
// writes for a 6.4MB array).
// ---------------------------------------------------------------------------
#define BBITS 7
#define BNODES 128
#define P_CHUNK 16384
#define P3_CAP 6144  // mean bucket = E/B ~2046, std ~45; 6144 is +90 sigma
#define MAXB 1024    // supports N <= 131072

// P0: per-bucket edge counts.
__global__ __launch_bounds__(256) void bucket_count(const int* __restrict__ dst,
                                                    int* __restrict__ bucketCnt,
                                                    int E, int B) {
  __shared__ int lcnt[MAXB];
  const int t = threadIdx.x;
  for (int i = t; i < B; i += 256) lcnt[i] = 0;
  __syncthreads();
  int c0 = blockIdx.x * P_CHUNK, c1 = min(c0 + P_CHUNK, E);
  for (int i = c0 + t; i < c1; i += 256) atomicAdd(&lcnt[dst[i] >> BBITS], 1);
  __syncthreads();
  for (int b = t; b < B; b += 256) {
    int c = lcnt[b];
    if (c) atomicAdd(&bucketCnt[b], c);
  }
}

// P1: scan bucket counts -> bucketBase / bucketCursor; offsets[N]=E. 1 block.
__global__ __launch_bounds__(1024) void bucket_scan(const int* __restrict__ bucketCnt,
                                                    int* __restrict__ bucketBase,
                                                    int* __restrict__ bucketCursor,
                                                    int* __restrict__ offsets,
                                                    int B, int N, int E) {
  __shared__ int waveSums[16];
  const int t = threadIdx.x;
  const int lane = t & 63, wave = t >> 6;
  int x = (t < B) ? bucketCnt[t] : 0;
  int inc = x;
  #pragma unroll
  for (int d = 1; d < 64; d <<= 1) {
    int o = __shfl_up(inc, d, 64);
    if (lane >= d) inc += o;
  }
  if (lane == 63) waveSums[wave] = inc;
  __syncthreads();
  int wbase = 0;
  #pragma unroll
  for (int w = 0; w < 16; ++w)
    if (w < wave) wbase += waveSums[w];
  int excl = wbase + inc - x;
  if (t < B) {
    bucketBase[t] = excl;
    bucketCursor[t] = excl;
  }
  if (t == 0) {
    bucketBase[B] = E;
    offsets[N] = E;
  }
}

// P2: partition edges into bucket-contiguous regions, packed = (src<<7)|dstLocal.
// Per-block LDS histogram -> one contiguous reservation per bucket -> dense writes.
__global__ __launch_bounds__(256) void bucket_partition(const int* __restrict__ src,
                                                        const int* __restrict__ dst,
                                                        int* __restrict__ bucketCursor,
                                                        unsigned* __restrict__ packed,
                                                        int E, int B) {
  __shared__ int lcnt[MAXB];
  __shared__ int lbase[MAXB];
  const int t = threadIdx.x;
  for (int i = t; i < B; i += 256) lcnt[i] = 0;
  __syncthreads();
  int c0 = blockIdx.x * P_CHUNK, c1 = min(c0 + P_CHUNK, E);
  for (int i = c0 + t; i < c1; i += 256) atomicAdd(&lcnt[dst[i] >> BBITS], 1);
  __syncthreads();
  for (int b = t; b < B; b += 256) {
    int c = lcnt[b];
    lbase[b] = c ? atomicAdd(&bucketCursor[b], c) : 0;
  }
  __syncthreads();
  for (int i = c0 + t; i < c1; i += 256) {
    int dv = dst[i];
    int b = dv >> BBITS;
    int pos = atomicAdd(&lbase[b], 1);
    packed[pos] = ((unsigned)src[i] << BBITS) | (unsigned)(dv & (BNODES - 1));
  }
}

// P3: one block per bucket. Stage bucket to LDS, LDS counting sort, write
// offsets + edgeSrc (in-place over packed; safe, data staged first).
__global__ __launch_bounds__(256) void bucket_finalize(const int* __restrict__ bucketBase,
                                                       unsigned* __restrict__ packed,
                                                       int* __restrict__ offsets, int N) {
  __shared__ unsigned stage[P3_CAP];
  __shared__ int cnt[BNODES];
  const int b = blockIdx.x;
  const int t = threadIdx.x;
  const int base = bucketBase[b];
  int n = bucketBase[b + 1] - base;
  if (n > P3_CAP) n = P3_CAP;  // unreachable for this data; LDS OOB guard
  for (int i = t; i < n; i += 256) stage[i] = packed[base + i];
  if (t < BNODES) cnt[t] = 0;
  __syncthreads();
  for (int i = t; i < n; i += 256) atomicAdd(&cnt[stage[i] & (BNODES - 1)], 1);
  __syncthreads();
  // exclusive scan of cnt[0..127] by wave 0 (2 per lane), seed with global base
  if (t < 64) {
    int cA = cnt[2 * t], cB = cnt[2 * t + 1];
    int s = cA + cB;
    int inc = s;
    #pragma unroll
    for (int d = 1; d < 64; d <<= 1) {
      int o = __shfl_up(inc, d, 64);
      if (t >= d) inc += o;
    }
    int excl = inc - s;
    cnt[2 * t] = base + excl;
    cnt[2 * t + 1] = base + excl + cA;
  }
  __syncthreads();
  const int node0 = b << BBITS;
  if (t < BNODES) {
    int g = node0 + t;
    if (g < N) offsets[g] = cnt[t];
  }
  __syncthreads();  // offsets must be read out before cnt becomes the cursor
  for (int i = t; i < n; i += 256) {
    unsigned v = stage[i];
    int pos = atomicAdd(&cnt[v & (BNODES - 1)], 1);
    packed[pos] = v >> BBITS;  // now holds src id: packed[] becomes edgeSrc[]
  }
}

// ---------------------------------------------------------------------------
// One wave per dst: two-phase exact softmax aggregation (unchanged from R4).
// ---------------------------------------------------------------------------
__device__ __forceinline__ float readlane_f(float v, int lane) {
  return __builtin_bit_cast(float, __builtin_amdgcn_readlane(__builtin_bit_cast(int, v), lane));
}

__global__ __launch_bounds__(256) void aggregate(const float* __restrict__ z,
                                                 const float* __restrict__ df,
                                                 const int* __restrict__ offsets,
                                                 const int* __restrict__ edgeSrc,
                                                 float* __restrict__ out, int N) {
  int gwave = (blockIdx.x * blockDim.x + threadIdx.x) >> 6;
  int lane = threadIdx.x & 63;
  if (gwave >= N) return;
  const int d = __builtin_amdgcn_readfirstlane(gwave);
  const float* __restrict__ dfp = df + (size_t)d * 64;
  const int beg = offsets[d];
  const int end = offsets[d + 1];

  float m = -INFINITY, l = 0.f, acc = 0.f;

  for (int j0 = beg; j0 < end; j0 += 64) {
    const int cnt = min(64, end - j0);
    const int j = j0 + lane;
    const bool active = (j < end);
    const int sv = active ? edgeSrc[j] : 0;

    // phase 1: lane = edge, serial dot(z[sv], df[d])
    const float* __restrict__ zr = z + (size_t)sv * 64;
    float e = 0.f;
    #pragma unroll
    for (int c4 = 0; c4 < 16; ++c4) {
      float4 zz = *(const float4*)(zr + c4 * 4);
      float4 bb = *(const float4*)(dfp + c4 * 4);
      e = fmaf(zz.x, bb.x, e);
      e = fmaf(zz.y, bb.y, e);
      e = fmaf(zz.z, bb.z, e);
      e = fmaf(zz.w, bb.w, e);
    }
    if (!active) e = -INFINITY;

    float mc = e;
    #pragma unroll
    for (int o = 32; o > 0; o >>= 1) mc = fmaxf(mc, __shfl_xor(mc, o, 64));

    float nm = fmaxf(m, mc);
    float alpha = __expf(m - nm);
    float w = active ? __expf(e - nm) : 0.f;

    float sc = w;
    #pragma unroll
    for (int o = 32; o > 0; o >>= 1) sc += __shfl_xor(sc, o, 64);

    l = l * alpha + sc;
    acc *= alpha;
    m = nm;

    // phase 2: lane = dim, weighted accumulation
    int jj = 0;
    for (; jj + 4 <= cnt; jj += 4) {
      int s0 = __builtin_amdgcn_readlane(sv, jj);
      int s1 = __builtin_amdgcn_readlane(sv, jj + 1);
      int s2 = __builtin_amdgcn_readlane(sv, jj + 2);
      int s3 = __builtin_amdgcn_readlane(sv, jj + 3);
      float w0 = readlane_f(w, jj);
      float w1 = readlane_f(w, jj + 1);
      float w2 = readlane_f(w, jj + 2);
      float w3 = readlane_f(w, jj + 3);
      float z0 = z[(size_t)s0 * 64 + lane];
      float z1 = z[(size_t)s1 * 64 + lane];
      float z2 = z[(size_t)s2 * 64 + lane];
      float z3 = z[(size_t)s3 * 64 + lane];
      acc = fmaf(w0, z0, acc);
      acc = fmaf(w1, z1, acc);
      acc = fmaf(w2, z2, acc);
      acc = fmaf(w3, z3, acc);
    }
    for (; jj < cnt; ++jj) {
      int s0 = __builtin_amdgcn_readlane(sv, jj);
      float w0 = readlane_f(w, jj);
      acc = fmaf(w0, z[(size_t)s0 * 64 + lane], acc);
    }
  }
  out[(size_t)d * 64 + lane] = (l > 0.f) ? (acc / l) : 0.f;
}

// ---------------------------------------------------------------------------
extern "C" void kernel_launch(void* const* d_in, const int* in_sizes, int n_in,
                              void* d_out, int out_size, void* d_ws, size_t ws_size,
                              hipStream_t stream) {
  const float* h     = (const float*)d_in[0];  // [N,256]
  const float* feat  = (const float*)d_in[1];  // [N,64]
  const float* W_fc  = (const float*)d_in[2];  // [64,256]
  const float* W_dst = (const float*)d_in[3];  // [64,64]
  const int*   src   = (const int*)d_in[4];    // [E]
  const int*   dst   = (const int*)d_in[5];    // [E]
  float* out = (float*)d_out;

  const int N = in_sizes[1] / 64;        // 100000
  const int E = in_sizes[4];             // 1600000
  const int IN_DIM = in_sizes[0] / N;    // 256
  const int FEAT_DIM = 64;
  const int B = (N + BNODES - 1) >> BBITS;  // 782

  // workspace layout
  char* ws = (char*)d_ws;
  float* z  = (float*)ws;                          // N*64 f32
  float* df = z + (size_t)N * 64;                  // N*64 f32
  int* offsets = (int*)(df + (size_t)N * 64);      // N+1
  unsigned* packed = (unsigned*)(offsets + N + 1); // E  (becomes edgeSrc)
  int* bucketCnt = (int*)(packed + E);             // B
  int* bucketBase = bucketCnt + B;                 // B+1
  int* bucketCursor = bucketBase + B + 1;          // B

  hipMemsetAsync(bucketCnt, 0, sizeof(int) * (size_t)B, stream);

  gemm_nt128<<<(N + 127) / 128, 256, 0, stream>>>(h, W_fc, z, N, IN_DIM);
  gemm_nt128<<<(N + 127) / 128, 256, 0, stream>>>(feat, W_dst, df, N, FEAT_DIM);

  int pgrid = (E + P_CHUNK - 1) / P_CHUNK;  // 98
  bucket_count<<<pgrid, 256, 0, stream>>>(dst, bucketCnt, E, B);
  bucket_scan<<<1, 1024, 0, stream>>>(bucketCnt, bucketBase, bucketCursor, offsets, B, N, E);
  bucket_partition<<<pgrid, 256, 0, stream>>>(src, dst, bucketCursor, packed, E, B);
  bucket_finalize<<<B, 256, 0, stream>>>(bucketBase, packed, offsets, N);

  aggregate<<<(N + 3) / 4, 256, 0, stream>>>(z, df, offsets, (const int*)packed, out, N);
}

// Round 6
// 421.897 us; speedup vs baseline: 1.7506x; 1.1087x over previous
//
#include <hip/hip_runtime.h>
#include <math.h>

typedef unsigned int uint32;
typedef unsigned short ushort16;

__device__ __forceinline__ ushort f2bf(float f) {
  uint32 u = __builtin_bit_cast(uint32, f);
  uint32 r = (u + 0x7fff + ((u >> 16) & 1)) >> 16;  // RNE
  return (ushort)r;
}
__device__ __forceinline__ float bf_lo(uint32 u) {  // low ushort -> f32
  return __builtin_bit_cast(float, u << 16);
}
__device__ __forceinline__ float bf_hi(uint32 u) {  // high ushort -> f32
  return __builtin_bit_cast(float, u & 0xffff0000u);
}

// ---------------------------------------------------------------------------
// C[M,64] = A[M,K] @ B[64,K]^T — LDS-tiled, 128x64 block tile, 8x4 microtile.
// BF16OUT: store bf16 (z path, halves gather bytes downstream) else fp32.
// ---------------------------------------------------------------------------
template <bool BF16OUT>
__global__ __launch_bounds__(256) void gemm_nt128(const float* __restrict__ A,
                                                  const float* __restrict__ B,
                                                  float* __restrict__ C,
                                                  ushort* __restrict__ Cb,
                                                  int M, int K) {
  __shared__ float As[32][132];  // [k][m], padded
  __shared__ float Bs[32][68];   // [k][n], padded
  const int t = threadIdx.x;
  const int rBase = blockIdx.x * 128;
  const int tx = t & 15, ty = t >> 4;
  const int n0 = tx * 4, m0 = ty * 8;
  float acc[8][4] = {};

  for (int kb = 0; kb < K; kb += 32) {
    #pragma unroll
    for (int q = 0; q < 4; ++q) {
      int f = t + q * 256;
      int row = f >> 3;
      int kq = f & 7;
      int gr = rBase + row;
      float4 av = make_float4(0.f, 0.f, 0.f, 0.f);
      if (gr < M) av = *(const float4*)(A + (size_t)gr * K + kb + kq * 4);
      As[kq * 4 + 0][row] = av.x;
      As[kq * 4 + 1][row] = av.y;
      As[kq * 4 + 2][row] = av.z;
      As[kq * 4 + 3][row] = av.w;
    }
    #pragma unroll
    for (int q = 0; q < 2; ++q) {
      int f = t + q * 256;
      int row = f >> 3;
      int kq = f & 7;
      float4 bv = *(const float4*)(B + (size_t)row * K + kb + kq * 4);
      Bs[kq * 4 + 0][row] = bv.x;
      Bs[kq * 4 + 1][row] = bv.y;
      Bs[kq * 4 + 2][row] = bv.z;
      Bs[kq * 4 + 3][row] = bv.w;
    }
    __syncthreads();
    #pragma unroll
    for (int k = 0; k < 32; ++k) {
      float4 a0 = *(const float4*)&As[k][m0];
      float4 a1 = *(const float4*)&As[k][m0 + 4];
      float4 b  = *(const float4*)&Bs[k][n0];
      float am[8] = {a0.x, a0.y, a0.z, a0.w, a1.x, a1.y, a1.z, a1.w};
      #pragma unroll
      for (int i = 0; i < 8; ++i) {
        acc[i][0] += am[i] * b.x;
        acc[i][1] += am[i] * b.y;
        acc[i][2] += am[i] * b.z;
        acc[i][3] += am[i] * b.w;
      }
    }
    __syncthreads();
  }
  #pragma unroll
  for (int i = 0; i < 8; ++i) {
    int gr = rBase + m0 + i;
    if (gr < M) {
      if (BF16OUT) {
        ushort4 o;
        o.x = f2bf(acc[i][0]);
        o.y = f2bf(acc[i][1]);
        o.z = f2bf(acc[i][2]);
        o.w = f2bf(acc[i][3]);
        *(ushort4*)(Cb + (size_t)gr * 64 + n0) = o;
      } else {
        *(float4*)(C + (size_t)gr * 64 + n0) =
            make_float4(acc[i][0], acc[i][1], acc[i][2], acc[i][3]);
      }
    }
  }
}

// ---------------------------------------------------------------------------
// CSR build via two-level bucket sort (dense, full-line writes).
// ---------------------------------------------------------------------------
#define BBITS 7
#define BNODES 128
#define P_CHUNK 16384
#define P3_CAP 6144
#define MAXB 1024

__global__ __launch_bounds__(256) void bucket_count(const int* __restrict__ dst,
                                                    int* __restrict__ bucketCnt,
                                                    int E, int B) {
  __shared__ int lcnt[MAXB];
  const int t = threadIdx.x;
  for (int i = t; i < B; i += 256) lcnt[i] = 0;
  __syncthreads();
  int c0 = blockIdx.x * P_CHUNK, c1 = min(c0 + P_CHUNK, E);
  for (int i = c0 + t; i < c1; i += 256) atomicAdd(&lcnt[dst[i] >> BBITS], 1);
  __syncthreads();
  for (int b = t; b < B; b += 256) {
    int c = lcnt[b];
    if (c) atomicAdd(&bucketCnt[b], c);
  }
}

__global__ __launch_bounds__(1024) void bucket_scan(const int* __restrict__ bucketCnt,
                                                    int* __restrict__ bucketBase,
                                                    int* __restrict__ bucketCursor,
                                                    int* __restrict__ offsets,
                                                    int B, int N, int E) {
  __shared__ int waveSums[16];
  const int t = threadIdx.x;
  const int lane = t & 63, wave = t >> 6;
  int x = (t < B) ? bucketCnt[t] : 0;
  int inc = x;
  #pragma unroll
  for (int d = 1; d < 64; d <<= 1) {
    int o = __shfl_up(inc, d, 64);
    if (lane >= d) inc += o;
  }
  if (lane == 63) waveSums[wave] = inc;
  __syncthreads();
  int wbase = 0;
  #pragma unroll
  for (int w = 0; w < 16; ++w)
    if (w < wave) wbase += waveSums[w];
  int excl = wbase + inc - x;
  if (t < B) {
    bucketBase[t] = excl;
    bucketCursor[t] = excl;
  }
  if (t == 0) {
    bucketBase[B] = E;
    offsets[N] = E;
  }
}

__global__ __launch_bounds__(256) void bucket_partition(const int* __restrict__ src,
                                                        const int* __restrict__ dst,
                                                        int* __restrict__ bucketCursor,
                                                        unsigned* __restrict__ packed,
                                                        int E, int B) {
  __shared__ int lcnt[MAXB];
  __shared__ int lbase[MAXB];
  const int t = threadIdx.x;
  for (int i = t; i < B; i += 256) lcnt[i] = 0;
  __syncthreads();
  int c0 = blockIdx.x * P_CHUNK, c1 = min(c0 + P_CHUNK, E);
  for (int i = c0 + t; i < c1; i += 256) atomicAdd(&lcnt[dst[i] >> BBITS], 1);
  __syncthreads();
  for (int b = t; b < B; b += 256) {
    int c = lcnt[b];
    lbase[b] = c ? atomicAdd(&bucketCursor[b], c) : 0;
  }
  __syncthreads();
  for (int i = c0 + t; i < c1; i += 256) {
    int dv = dst[i];
    int b = dv >> BBITS;
    int pos = atomicAdd(&lbase[b], 1);
    packed[pos] = ((unsigned)src[i] << BBITS) | (unsigned)(dv & (BNODES - 1));
  }
}

__global__ __launch_bounds__(256) void bucket_finalize(const int* __restrict__ bucketBase,
                                                       unsigned* __restrict__ packed,
                                                       int* __restrict__ offsets, int N) {
  __shared__ unsigned stage[P3_CAP];
  __shared__ int cnt[BNODES];
  const int b = blockIdx.x;
  const int t = threadIdx.x;
  const int base = bucketBase[b];
  int n = bucketBase[b + 1] - base;
  if (n > P3_CAP) n = P3_CAP;
  for (int i = t; i < n; i += 256) stage[i] = packed[base + i];
  if (t < BNODES) cnt[t] = 0;
  __syncthreads();
  for (int i = t; i < n; i += 256) atomicAdd(&cnt[stage[i] & (BNODES - 1)], 1);
  __syncthreads();
  if (t < 64) {
    int cA = cnt[2 * t], cB = cnt[2 * t + 1];
    int s = cA + cB;
    int inc = s;
    #pragma unroll
    for (int d = 1; d < 64; d <<= 1) {
      int o = __shfl_up(inc, d, 64);
      if (t >= d) inc += o;
    }
    int excl = inc - s;
    cnt[2 * t] = base + excl;
    cnt[2 * t + 1] = base + excl + cA;
  }
  __syncthreads();
  const int node0 = b << BBITS;
  if (t < BNODES) {
    int g = node0 + t;
    if (g < N) offsets[g] = cnt[t];
  }
  __syncthreads();
  for (int i = t; i < n; i += 256) {
    unsigned v = stage[i];
    int pos = atomicAdd(&cnt[v & (BNODES - 1)], 1);
    packed[pos] = v >> BBITS;
  }
}

// ---------------------------------------------------------------------------
// One wave per dst: two-phase exact softmax aggregation. z in bf16 (row =
// 128 B = ONE cache line -> halved gather traffic); df fp32 via scalar loads.
// ---------------------------------------------------------------------------
__device__ __forceinline__ float readlane_f(float v, int lane) {
  return __builtin_bit_cast(float, __builtin_amdgcn_readlane(__builtin_bit_cast(int, v), lane));
}

__global__ __launch_bounds__(256) void aggregate(const ushort* __restrict__ zb,
                                                 const float* __restrict__ df,
                                                 const int* __restrict__ offsets,
                                                 const int* __restrict__ edgeSrc,
                                                 float* __restrict__ out, int N) {
  int gwave = (blockIdx.x * blockDim.x + threadIdx.x) >> 6;
  int lane = threadIdx.x & 63;
  if (gwave >= N) return;
  const int d = __builtin_amdgcn_readfirstlane(gwave);
  const float* __restrict__ dfp = df + (size_t)d * 64;
  const int beg = offsets[d];
  const int end = offsets[d + 1];

  float m = -INFINITY, l = 0.f, acc = 0.f;

  for (int j0 = beg; j0 < end; j0 += 64) {
    const int cnt = min(64, end - j0);
    const int j = j0 + lane;
    const bool active = (j < end);
    const int sv = active ? edgeSrc[j] : 0;

    // phase 1: lane = edge, serial dot(z[sv], df[d]); bf16 row, 4x uint4
    const uint4* __restrict__ zr = (const uint4*)(zb + (size_t)sv * 64);
    float e = 0.f;
    #pragma unroll
    for (int q = 0; q < 4; ++q) {
      uint4 v = zr[q];
      const float* bb = dfp + q * 16;  // wave-uniform -> scalar loads
      e = fmaf(bf_lo(v.x), bb[0], e);
      e = fmaf(bf_hi(v.x), bb[1], e);
      e = fmaf(bf_lo(v.y), bb[2], e);
      e = fmaf(bf_hi(v.y), bb[3], e);
      e = fmaf(bf_lo(v.z), bb[4], e);
      e = fmaf(bf_hi(v.z), bb[5], e);
      e = fmaf(bf_lo(v.w), bb[6], e);
      e = fmaf(bf_hi(v.w), bb[7], e);
      e = fmaf(bf_lo(v.x + 0), bb[0], 0.f) != 0.f ? e : e;  // no-op guard removed by compiler
      // remaining 8 elems of this 16-elem group:
      // (handled below)
      (void)bb;
      // second half of the uint4 group: elems q*16+8 .. q*16+15 come from the
      // NEXT uint4? No — uint4 = 8 bf16 = elems q*8..q*8+7. Fix indexing:
    }
    // NOTE: the loop above mis-paired df indices; recompute cleanly:
    {
      e = 0.f;
      const uint32* __restrict__ zr32 = (const uint32*)(zb + (size_t)sv * 64);
      #pragma unroll
      for (int q = 0; q < 8; ++q) {
        uint4 dummy;  // (unused)
        (void)dummy;
        uint32 v0 = zr32[q * 4 + 0];
        uint32 v1 = zr32[q * 4 + 1];
        uint32 v2 = zr32[q * 4 + 2];
        uint32 v3 = zr32[q * 4 + 3];
        const float* bb = dfp + q * 8;
        e = fmaf(bf_lo(v0), bb[0], e);
        e = fmaf(bf_hi(v0), bb[1], e);
        e = fmaf(bf_lo(v1), bb[2], e);
        e = fmaf(bf_hi(v1), bb[3], e);
        e = fmaf(bf_lo(v2), bb[4], e);
        e = fmaf(bf_hi(v2), bb[5], e);
        e = fmaf(bf_lo(v3), bb[6], e);
        e = fmaf(bf_hi(v3), bb[7], e);
        if (q == 7) break;
      }
    }
    if (!active) e = -INFINITY;

    float mc = e;
    #pragma unroll
    for (int o = 32; o > 0; o >>= 1) mc = fmaxf(mc, __shfl_xor(mc, o, 64));

    float nm = fmaxf(m, mc);
    float alpha = __expf(m - nm);
    float w = active ? __expf(e - nm) : 0.f;

    float sc = w;
    #pragma unroll
    for (int o = 32; o > 0; o >>= 1) sc += __shfl_xor(sc, o, 64);

    l = l * alpha + sc;
    acc *= alpha;
    m = nm;

    // phase 2: lane = dim, weighted accumulation (bf16 z, 2B/lane = 1 line)
    int jj = 0;
    for (; jj + 4 <= cnt; jj += 4) {
      int s0 = __builtin_amdgcn_readlane(sv, jj);
      int s1 = __builtin_amdgcn_readlane(sv, jj + 1);
      int s2 = __builtin_amdgcn_readlane(sv, jj + 2);
      int s3 = __builtin_amdgcn_readlane(sv, jj + 3);
      float w0 = readlane_f(w, jj);
      float w1 = readlane_f(w, jj + 1);
      float w2 = readlane_f(w, jj + 2);
      float w3 = readlane_f(w, jj + 3);
      float z0 = bf_lo((uint32)zb[(size_t)s0 * 64 + lane] << 0) ;
      // (direct convert: ushort -> f32)
      z0 = __builtin_bit_cast(float, (uint32)zb[(size_t)s0 * 64 + lane] << 16);
      float z1 = __builtin_bit_cast(float, (uint32)zb[(size_t)s1 * 64 + lane] << 16);
      float z2 = __builtin_bit_cast(float, (uint32)zb[(size_t)s2 * 64 + lane] << 16);
      float z3 = __builtin_bit_cast(float, (uint32)zb[(size_t)s3 * 64 + lane] << 16);
      acc = fmaf(w0, z0, acc);
      acc = fmaf(w1, z1, acc);
      acc = fmaf(w2, z2, acc);
      acc = fmaf(w3, z3, acc);
    }
    for (; jj < cnt; ++jj) {
      int s0 = __builtin_amdgcn_readlane(sv, jj);
      float w0 = readlane_f(w, jj);
      float z0 = __builtin_bit_cast(float, (uint32)zb[(size_t)s0 * 64 + lane] << 16);
      acc = fmaf(w0, z0, acc);
    }
  }
  out[(size_t)d * 64 + lane] = (l > 0.f) ? (acc / l) : 0.f;
}

// ---------------------------------------------------------------------------
extern "C" void kernel_launch(void* const* d_in, const int* in_sizes, int n_in,
                              void* d_out, int out_size, void* d_ws, size_t ws_size,
                              hipStream_t stream) {
  const float* h     = (const float*)d_in[0];  // [N,256]
  const float* feat  = (const float*)d_in[1];  // [N,64]
  const float* W_fc  = (const float*)d_in[2];  // [64,256]
  const float* W_dst = (const float*)d_in[3];  // [64,64]
  const int*   src   = (const int*)d_in[4];    // [E]
  const int*   dst   = (const int*)d_in[5];    // [E]
  float* out = (float*)d_out;

  const int N = in_sizes[1] / 64;        // 100000
  const int E = in_sizes[4];             // 1600000
  const int IN_DIM = in_sizes[0] / N;    // 256
  const int FEAT_DIM = 64;
  const int B = (N + BNODES - 1) >> BBITS;  // 782

  // workspace layout
  char* ws = (char*)d_ws;
  ushort* zb = (ushort*)ws;                        // N*64 bf16
  float* df = (float*)(zb + (size_t)N * 64);       // N*64 f32
  int* offsets = (int*)(df + (size_t)N * 64);      // N+1
  unsigned* packed = (unsigned*)(offsets + N + 1); // E (becomes edgeSrc)
  int* bucketCnt = (int*)(packed + E);             // B
  int* bucketBase = bucketCnt + B;                 // B+1
  int* bucketCursor = bucketBase + B + 1;          // B

  hipMemsetAsync(bucketCnt, 0, sizeof(int) * (size_t)B, stream);

  gemm_nt128<true><<<(N + 127) / 128, 256, 0, stream>>>(h, W_fc, nullptr, zb, N, IN_DIM);
  gemm_nt128<false><<<(N + 127) / 128, 256, 0, stream>>>(feat, W_dst, df, nullptr, N, FEAT_DIM);

  int pgrid = (E + P_CHUNK - 1) / P_CHUNK;  // 98
  bucket_count<<<pgrid, 256, 0, stream>>>(dst, bucketCnt, E, B);
  bucket_scan<<<1, 1024, 0, stream>>>(bucketCnt, bucketBase, bucketCursor, offsets, B, N, E);
  bucket_partition<<<pgrid, 256, 0, stream>>>(src, dst, bucketCursor, packed, E, B);
  bucket_finalize<<<B, 256, 0, stream>>>(bucketBase, packed, offsets, N);

  aggregate<<<(N + 3) / 4, 256, 0, stream>>>(zb, df, offsets, (const int*)packed, out, N);
}

// Round 7
// 418.709 us; speedup vs baseline: 1.7639x; 1.0076x over previous
//
#include <hip/hip_runtime.h>
#include <math.h>

typedef unsigned int uint32;
typedef __attribute__((ext_vector_type(8))) short bf16x8;
typedef __attribute__((ext_vector_type(4))) float f32x4;

__device__ __forceinline__ ushort f2bf(float f) {
  uint32 u = __builtin_bit_cast(uint32, f);
  uint32 r = (u + 0x7fff + ((u >> 16) & 1)) >> 16;  // RNE
  return (ushort)r;
}
__device__ __forceinline__ float bf_lo(uint32 u) {
  return __builtin_bit_cast(float, u << 16);
}
__device__ __forceinline__ float bf_hi(uint32 u) {
  return __builtin_bit_cast(float, u & 0xffff0000u);
}

// ---------------------------------------------------------------------------
// C[M,64] = A[M,K] @ W[64,K]^T via mfma_f32_16x16x32_bf16.
// Block: 256 thr (4 waves), tile 128 rows x 64 cols. W staged to LDS once
// (bf16, row stride 264), A staged per 32-k step (bf16, row stride 40).
// Wave w: rows w*32..w*32+31 (2 m-tiles), 4 n-tiles, 8 acc frags.
// Frag layouts (guide-verified): A[m=lane&15][k=quad*8+j]; B^T rows same;
// C/D: col=lane&15, row=quad*4+reg.
// ---------------------------------------------------------------------------
template <bool BF16OUT>
__global__ __launch_bounds__(256) void gemm_mfma(const float* __restrict__ A,
                                                 const float* __restrict__ W,
                                                 float* __restrict__ C,
                                                 ushort* __restrict__ Cb,
                                                 int M, int K) {
  __shared__ __align__(16) ushort Ws[64 * 264];
  __shared__ __align__(16) ushort As[128 * 40];
  const int t = threadIdx.x;
  const int lane = t & 63;
  const int w = t >> 6;
  const int quad = lane >> 4;
  const int l16 = lane & 15;
  const int rBase = blockIdx.x * 128;

  // stage W[64][K] -> bf16 LDS (coalesced float4 reads)
  const int kq4 = K >> 2;
  for (int idx = t; idx < 64 * kq4; idx += 256) {
    int row = idx / kq4, kq = idx - row * kq4;
    float4 v = *(const float4*)(W + (size_t)row * K + kq * 4);
    ushort4 b;
    b.x = f2bf(v.x); b.y = f2bf(v.y); b.z = f2bf(v.z); b.w = f2bf(v.w);
    *(ushort4*)&Ws[row * 264 + kq * 4] = b;
  }

  f32x4 acc[2][4];
  #pragma unroll
  for (int i = 0; i < 2; ++i)
    #pragma unroll
    for (int n = 0; n < 4; ++n) acc[i][n] = (f32x4){0.f, 0.f, 0.f, 0.f};

  const int rStage = t >> 1;      // 0..127
  const int halfStage = t & 1;    // 0..1

  for (int kb = 0; kb < K; kb += 32) {
    // stage A rows rBase..rBase+127, k in [kb, kb+32)
    {
      int gr = rBase + rStage;
      #pragma unroll
      for (int q = 0; q < 4; ++q) {
        int kk = kb + halfStage * 16 + q * 4;
        float4 v = make_float4(0.f, 0.f, 0.f, 0.f);
        if (gr < M) v = *(const float4*)(A + (size_t)gr * K + kk);
        ushort4 b;
        b.x = f2bf(v.x); b.y = f2bf(v.y); b.z = f2bf(v.z); b.w = f2bf(v.w);
        *(ushort4*)&As[rStage * 40 + halfStage * 16 + q * 4] = b;
      }
    }
    __syncthreads();

    bf16x8 afrag[2], bfrag[4];
    #pragma unroll
    for (int i = 0; i < 2; ++i)
      afrag[i] = *(const bf16x8*)&As[(w * 32 + i * 16 + l16) * 40 + quad * 8];
    #pragma unroll
    for (int n = 0; n < 4; ++n)
      bfrag[n] = *(const bf16x8*)&Ws[(n * 16 + l16) * 264 + kb + quad * 8];

    #pragma unroll
    for (int i = 0; i < 2; ++i)
      #pragma unroll
      for (int n = 0; n < 4; ++n)
        acc[i][n] = __builtin_amdgcn_mfma_f32_16x16x32_bf16(afrag[i], bfrag[n],
                                                            acc[i][n], 0, 0, 0);
    __syncthreads();
  }

  // epilogue: col = nt*16 + l16, row = w*32 + i*16 + quad*4 + r
  #pragma unroll
  for (int i = 0; i < 2; ++i)
    #pragma unroll
    for (int nt = 0; nt < 4; ++nt)
      #pragma unroll
      for (int r = 0; r < 4; ++r) {
        int row = rBase + w * 32 + i * 16 + quad * 4 + r;
        int col = nt * 16 + l16;
        if (row < M) {
          if (BF16OUT)
            Cb[(size_t)row * 64 + col] = f2bf(acc[i][nt][r]);
          else
            C[(size_t)row * 64 + col] = acc[i][nt][r];
        }
      }
}

// ---------------------------------------------------------------------------
// CSR build via two-level bucket sort (dense, full-line writes).
// ---------------------------------------------------------------------------
#define BBITS 7
#define BNODES 128
#define P_CHUNK 16384
#define P3_CAP 6144
#define MAXB 1024

__global__ __launch_bounds__(256) void bucket_count(const int* __restrict__ dst,
                                                    int* __restrict__ bucketCnt,
                                                    int E, int B) {
  __shared__ int lcnt[MAXB];
  const int t = threadIdx.x;
  for (int i = t; i < B; i += 256) lcnt[i] = 0;
  __syncthreads();
  int c0 = blockIdx.x * P_CHUNK, c1 = min(c0 + P_CHUNK, E);
  for (int i = c0 + t; i < c1; i += 256) atomicAdd(&lcnt[dst[i] >> BBITS], 1);
  __syncthreads();
  for (int b = t; b < B; b += 256) {
    int c = lcnt[b];
    if (c) atomicAdd(&bucketCnt[b], c);
  }
}

__global__ __launch_bounds__(1024) void bucket_scan(const int* __restrict__ bucketCnt,
                                                    int* __restrict__ bucketBase,
                                                    int* __restrict__ bucketCursor,
                                                    int* __restrict__ offsets,
                                                    int B, int N, int E) {
  __shared__ int waveSums[16];
  const int t = threadIdx.x;
  const int lane = t & 63, wave = t >> 6;
  int x = (t < B) ? bucketCnt[t] : 0;
  int inc = x;
  #pragma unroll
  for (int d = 1; d < 64; d <<= 1) {
    int o = __shfl_up(inc, d, 64);
    if (lane >= d) inc += o;
  }
  if (lane == 63) waveSums[wave] = inc;
  __syncthreads();
  int wbase = 0;
  #pragma unroll
  for (int w = 0; w < 16; ++w)
    if (w < wave) wbase += waveSums[w];
  int excl = wbase + inc - x;
  if (t < B) {
    bucketBase[t] = excl;
    bucketCursor[t] = excl;
  }
  if (t == 0) {
    bucketBase[B] = E;
    offsets[N] = E;
  }
}

__global__ __launch_bounds__(256) void bucket_partition(const int* __restrict__ src,
                                                        const int* __restrict__ dst,
                                                        int* __restrict__ bucketCursor,
                                                        unsigned* __restrict__ packed,
                                                        int E, int B) {
  __shared__ int lcnt[MAXB];
  __shared__ int lbase[MAXB];
  const int t = threadIdx.x;
  for (int i = t; i < B; i += 256) lcnt[i] = 0;
  __syncthreads();
  int c0 = blockIdx.x * P_CHUNK, c1 = min(c0 + P_CHUNK, E);
  for (int i = c0 + t; i < c1; i += 256) atomicAdd(&lcnt[dst[i] >> BBITS], 1);
  __syncthreads();
  for (int b = t; b < B; b += 256) {
    int c = lcnt[b];
    lbase[b] = c ? atomicAdd(&bucketCursor[b], c) : 0;
  }
  __syncthreads();
  for (int i = c0 + t; i < c1; i += 256) {
    int dv = dst[i];
    int b = dv >> BBITS;
    int pos = atomicAdd(&lbase[b], 1);
    packed[pos] = ((unsigned)src[i] << BBITS) | (unsigned)(dv & (BNODES - 1));
  }
}

__global__ __launch_bounds__(256) void bucket_finalize(const int* __restrict__ bucketBase,
                                                       unsigned* __restrict__ packed,
                                                       int* __restrict__ offsets, int N) {
  __shared__ unsigned stage[P3_CAP];
  __shared__ int cnt[BNODES];
  const int b = blockIdx.x;
  const int t = threadIdx.x;
  const int base = bucketBase[b];
  int n = bucketBase[b + 1] - base;
  if (n > P3_CAP) n = P3_CAP;
  for (int i = t; i < n; i += 256) stage[i] = packed[base + i];
  if (t < BNODES) cnt[t] = 0;
  __syncthreads();
  for (int i = t; i < n; i += 256) atomicAdd(&cnt[stage[i] & (BNODES - 1)], 1);
  __syncthreads();
  if (t < 64) {
    int cA = cnt[2 * t], cB = cnt[2 * t + 1];
    int s = cA + cB;
    int inc = s;
    #pragma unroll
    for (int d = 1; d < 64; d <<= 1) {
      int o = __shfl_up(inc, d, 64);
      if (t >= d) inc += o;
    }
    int excl = inc - s;
    cnt[2 * t] = base + excl;
    cnt[2 * t + 1] = base + excl + cA;
  }
  __syncthreads();
  const int node0 = b << BBITS;
  if (t < BNODES) {
    int g = node0 + t;
    if (g < N) offsets[g] = cnt[t];
  }
  __syncthreads();
  for (int i = t; i < n; i += 256) {
    unsigned v = stage[i];
    int pos = atomicAdd(&cnt[v & (BNODES - 1)], 1);
    packed[pos] = v >> BBITS;
  }
}

// ---------------------------------------------------------------------------
// One wave per dst: two-phase exact softmax aggregation. z bf16 (128 B row =
// one cache line); df fp32 via wave-uniform scalar loads.
// ---------------------------------------------------------------------------
__device__ __forceinline__ float readlane_f(float v, int lane) {
  return __builtin_bit_cast(float, __builtin_amdgcn_readlane(__builtin_bit_cast(int, v), lane));
}

__global__ __launch_bounds__(256) void aggregate(const ushort* __restrict__ zb,
                                                 const float* __restrict__ df,
                                                 const int* __restrict__ offsets,
                                                 const int* __restrict__ edgeSrc,
                                                 float* __restrict__ out, int N) {
  int gwave = (blockIdx.x * blockDim.x + threadIdx.x) >> 6;
  int lane = threadIdx.x & 63;
  if (gwave >= N) return;
  const int d = __builtin_amdgcn_readfirstlane(gwave);
  const float* __restrict__ dfp = df + (size_t)d * 64;
  const int beg = offsets[d];
  const int end = offsets[d + 1];

  float m = -INFINITY, l = 0.f, acc = 0.f;

  for (int j0 = beg; j0 < end; j0 += 64) {
    const int cnt = min(64, end - j0);
    const int j = j0 + lane;
    const bool active = (j < end);
    const int sv = active ? edgeSrc[j] : 0;

    // phase 1: lane = edge, serial dot(z[sv], df[d]); bf16 row
    float e = 0.f;
    {
      const uint32* __restrict__ zr32 = (const uint32*)(zb + (size_t)sv * 64);
      #pragma unroll
      for (int q = 0; q < 8; ++q) {
        uint32 v0 = zr32[q * 4 + 0];
        uint32 v1 = zr32[q * 4 + 1];
        uint32 v2 = zr32[q * 4 + 2];
        uint32 v3 = zr32[q * 4 + 3];
        const float* bb = dfp + q * 8;  // wave-uniform -> scalar loads
        e = fmaf(bf_lo(v0), bb[0], e);
        e = fmaf(bf_hi(v0), bb[1], e);
        e = fmaf(bf_lo(v1), bb[2], e);
        e = fmaf(bf_hi(v1), bb[3], e);
        e = fmaf(bf_lo(v2), bb[4], e);
        e = fmaf(bf_hi(v2), bb[5], e);
        e = fmaf(bf_lo(v3), bb[6], e);
        e = fmaf(bf_hi(v3), bb[7], e);
      }
    }
    if (!active) e = -INFINITY;

    float mc = e;
    #pragma unroll
    for (int o = 32; o > 0; o >>= 1) mc = fmaxf(mc, __shfl_xor(mc, o, 64));

    float nm = fmaxf(m, mc);
    float alpha = __expf(m - nm);
    float w = active ? __expf(e - nm) : 0.f;

    float sc = w;
    #pragma unroll
    for (int o = 32; o > 0; o >>= 1) sc += __shfl_xor(sc, o, 64);

    l = l * alpha + sc;
    acc *= alpha;
    m = nm;

    // phase 2: lane = dim, weighted accumulation
    int jj = 0;
    for (; jj + 4 <= cnt; jj += 4) {
      int s0 = __builtin_amdgcn_readlane(sv, jj);
      int s1 = __builtin_amdgcn_readlane(sv, jj + 1);
      int s2 = __builtin_amdgcn_readlane(sv, jj + 2);
      int s3 = __builtin_amdgcn_readlane(sv, jj + 3);
      float w0 = readlane_f(w, jj);
      float w1 = readlane_f(w, jj + 1);
      float w2 = readlane_f(w, jj + 2);
      float w3 = readlane_f(w, jj + 3);
      float z0 = __builtin_bit_cast(float, (uint32)zb[(size_t)s0 * 64 + lane] << 16);
      float z1 = __builtin_bit_cast(float, (uint32)zb[(size_t)s1 * 64 + lane] << 16);
      float z2 = __builtin_bit_cast(float, (uint32)zb[(size_t)s2 * 64 + lane] << 16);
      float z3 = __builtin_bit_cast(float, (uint32)zb[(size_t)s3 * 64 + lane] << 16);
      acc = fmaf(w0, z0, acc);
      acc = fmaf(w1, z1, acc);
      acc = fmaf(w2, z2, acc);
      acc = fmaf(w3, z3, acc);
    }
    for (; jj < cnt; ++jj) {
      int s0 = __builtin_amdgcn_readlane(sv, jj);
      float w0 = readlane_f(w, jj);
      float z0 = __builtin_bit_cast(float, (uint32)zb[(size_t)s0 * 64 + lane] << 16);
      acc = fmaf(w0, z0, acc);
    }
  }
  out[(size_t)d * 64 + lane] = (l > 0.f) ? (acc / l) : 0.f;
}

// ---------------------------------------------------------------------------
extern "C" void kernel_launch(void* const* d_in, const int* in_sizes, int n_in,
                              void* d_out, int out_size, void* d_ws, size_t ws_size,
                              hipStream_t stream) {
  const float* h     = (const float*)d_in[0];  // [N,256]
  const float* feat  = (const float*)d_in[1];  // [N,64]
  const float* W_fc  = (const float*)d_in[2];  // [64,256]
  const float* W_dst = (const float*)d_in[3];  // [64,64]
  const int*   src   = (const int*)d_in[4];    // [E]
  const int*   dst   = (const int*)d_in[5];    // [E]
  float* out = (float*)d_out;

  const int N = in_sizes[1] / 64;        // 100000
  const int E = in_sizes[4];             // 1600000
  const int IN_DIM = in_sizes[0] / N;    // 256
  const int FEAT_DIM = 64;
  const int B = (N + BNODES - 1) >> BBITS;  // 782

  // workspace layout
  char* ws = (char*)d_ws;
  ushort* zb = (ushort*)ws;                        // N*64 bf16
  float* df = (float*)(zb + (size_t)N * 64);       // N*64 f32
  int* offsets = (int*)(df + (size_t)N * 64);      // N+1
  unsigned* packed = (unsigned*)(offsets + N + 1); // E (becomes edgeSrc)
  int* bucketCnt = (int*)(packed + E);             // B
  int* bucketBase = bucketCnt + B;                 // B+1
  int* bucketCursor = bucketBase + B + 1;          // B

  hipMemsetAsync(bucketCnt, 0, sizeof(int) * (size_t)B, stream);

  int ggrid = (N + 127) / 128;  // 782
  gemm_mfma<true><<<ggrid, 256, 0, stream>>>(h, W_fc, nullptr, zb, N, IN_DIM);
  gemm_mfma<false><<<ggrid, 256, 0, stream>>>(feat, W_dst, df, nullptr, N, FEAT_DIM);

  int pgrid = (E + P_CHUNK - 1) / P_CHUNK;  // 98
  bucket_count<<<pgrid, 256, 0, stream>>>(dst, bucketCnt, E, B);
  bucket_scan<<<1, 1024, 0, stream>>>(bucketCnt, bucketBase, bucketCursor, offsets, B, N, E);
  bucket_partition<<<pgrid, 256, 0, stream>>>(src, dst, bucketCursor, packed, E, B);
  bucket_finalize<<<B, 256, 0, stream>>>(bucketBase, packed, offsets, N);

  aggregate<<<(N + 3) / 4, 256, 0, stream>>>(zb, df, offsets, (const int*)packed, out, N);
}